// Round 3
// baseline (12457.544 us; speedup 1.0000x reference)
//
#include <hip/hip_runtime.h>

typedef _Float16 f16;
typedef _Float16 f16x4 __attribute__((ext_vector_type(4)));
typedef _Float16 f16x8 __attribute__((ext_vector_type(8)));
typedef float f32x4 __attribute__((ext_vector_type(4)));
typedef unsigned u32x4 __attribute__((ext_vector_type(4)));

#define BB 8
#define TT 1024
#define HH 768
#define HDD 384
#define NG 1536        // 4*HDD
#define SS 16
#define MTOT (BB*TT)   // 8192

// ---------------- casts ----------------
__global__ void cast_f32_f16_k(const float* __restrict__ src, f16* __restrict__ dst, int n) {
    int i = blockIdx.x*256 + threadIdx.x;
    if (i < n) dst[i] = (f16)src[i];
}

__global__ void bias_sum_k(const float* a0,const float* b0,const float* a1,const float* b1,
                           const float* a2,const float* b2,const float* a3,const float* b3,
                           float* __restrict__ out) {
    int i = blockIdx.x*256 + threadIdx.x;
    if (i >= 4*NG) return;
    int which = i/NG, j = i - which*NG;
    const float* pa = which==0?a0:which==1?a1:which==2?a2:a3;
    const float* pb = which==0?b0:which==1?b1:which==2?b2:b3;
    out[i] = pa[j] + pb[j];
}

__global__ void embed_cast_k(const int* __restrict__ ids, const float* __restrict__ emb,
                             f16* __restrict__ x) {
    int i = blockIdx.x*256 + threadIdx.x;   // < MTOT*HH
    if (i < MTOT*HH) {
        int m = i / HH;
        int k = i - m*HH;
        x[i] = (f16)emb[(size_t)ids[m]*HH + k];
    }
}

// ---------------- input GEMM ----------------
// R8 layout: pre[dir][wb][t][b][lc][gate], wb=c/16 (0..23), lc=c%16.
// Per (wb,t): 512 f16 = 1KB contiguous (bulk global_load_lds staging);
// inner order [b][lc][gate] makes the per-step ds_read_b64 4-way instead of
// 16-way bank-conflicted (64B-stride pattern removed).
__launch_bounds__(256,1)
__global__ void gemm_pre_k(const f16* __restrict__ A, const f16* __restrict__ Wf,
                           const f16* __restrict__ Wb, const float* __restrict__ bsum2,
                           f16* __restrict__ pre) {
    int d = blockIdx.z;
    const f16* Wt = d ? Wb : Wf;
    const float* bs = bsum2 + d*NG;
    f16* out = pre + (size_t)d*MTOT*NG;
    int m0 = blockIdx.x*64, n0 = blockIdx.y*64;
    __shared__ f16 As[64*72];
    __shared__ f16 Bs[64*72];
    int tid = threadIdx.x;
    int w = tid>>6, l = tid&63;
    int lrow = l&15, lgrp = l>>4;
    int mq = (w>>1)*32, nq = (w&1)*32;
    f32x4 acc00={0,0,0,0}, acc01={0,0,0,0}, acc10={0,0,0,0}, acc11={0,0,0,0};

    for (int k0=0; k0<HH; k0+=64) {
        __syncthreads();
        #pragma unroll
        for (int r=0;r<2;r++) {
            int c = tid + 256*r;
            int row = c>>3, seg = c&7;
            *(f16x8*)(As + row*72 + seg*8) = *(const f16x8*)(A  + ((size_t)(m0+row))*HH + k0 + seg*8);
            *(f16x8*)(Bs + row*72 + seg*8) = *(const f16x8*)(Wt + ((size_t)(n0+row))*HH + k0 + seg*8);
        }
        __syncthreads();
        #pragma unroll
        for (int kk=0; kk<64; kk+=32) {
            f16x8 a0 = *(const f16x8*)(As + (mq+lrow)*72    + kk + lgrp*8);
            f16x8 a1 = *(const f16x8*)(As + (mq+16+lrow)*72 + kk + lgrp*8);
            f16x8 b0 = *(const f16x8*)(Bs + (nq+lrow)*72    + kk + lgrp*8);
            f16x8 b1 = *(const f16x8*)(Bs + (nq+16+lrow)*72 + kk + lgrp*8);
            acc00 = __builtin_amdgcn_mfma_f32_16x16x32_f16(a0,b0,acc00,0,0,0);
            acc01 = __builtin_amdgcn_mfma_f32_16x16x32_f16(a0,b1,acc01,0,0,0);
            acc10 = __builtin_amdgcn_mfma_f32_16x16x32_f16(a1,b0,acc10,0,0,0);
            acc11 = __builtin_amdgcn_mfma_f32_16x16x32_f16(a1,b1,acc11,0,0,0);
        }
    }
    #pragma unroll
    for (int mt=0;mt<2;mt++) {
        #pragma unroll
        for (int nt=0;nt<2;nt++) {
            f32x4 a = (mt==0)?(nt==0?acc00:acc01):(nt==0?acc10:acc11);
            int col = n0 + nq + nt*16 + lrow;     // 0..1535 = gate*384 + c
            int gate = col / HDD;
            int c = col - gate*HDD;               // 0..383
            float bv = bs[col];
            size_t base = (size_t)(c>>4)*524288 + (size_t)(c&15)*4 + gate;
            #pragma unroll
            for (int r=0;r<4;r++) {
                int row = m0 + mq + mt*16 + lgrp*4 + r;   // b*1024 + t
                int b = row >> 10, t = row & 1023;
                out[base + (size_t)t*512 + b*64] = (f16)(a[r] + bv);
            }
        }
    }
}

// ---- helpers ----
__device__ __forceinline__ unsigned get_xcc() {
    unsigned x;
    asm("s_getreg_b32 %0, hwreg(HW_REG_XCC_ID)" : "=s"(x));
    return x & 7u;
}
__device__ __forceinline__ void gload_lds16(const f16* g, f16* lds) {
    // wave-uniform LDS dest (HW adds lane*16B); per-lane global src
    __builtin_amdgcn_global_load_lds(
        (const __attribute__((address_space(1))) void*)g,
        (__attribute__((address_space(3))) void*)lds, 16, 0, 0);
}

// 12 coalesced dwordx4 sc0 loads (L1-bypass) + one vmcnt(0).
// kk-stride = 1024B; bases at kk=0,4,8 keep offsets under the 13-bit limit.
#define POLL12(v, a0_, a1_, a2_)                                              \
    asm volatile(                                                             \
        "global_load_dwordx4 %[v0], %[a0], off sc0\n\t"                       \
        "global_load_dwordx4 %[v1], %[a0], off offset:1024 sc0\n\t"           \
        "global_load_dwordx4 %[v2], %[a0], off offset:2048 sc0\n\t"           \
        "global_load_dwordx4 %[v3], %[a0], off offset:3072 sc0\n\t"           \
        "global_load_dwordx4 %[v4], %[a1], off sc0\n\t"                       \
        "global_load_dwordx4 %[v5], %[a1], off offset:1024 sc0\n\t"           \
        "global_load_dwordx4 %[v6], %[a1], off offset:2048 sc0\n\t"           \
        "global_load_dwordx4 %[v7], %[a1], off offset:3072 sc0\n\t"           \
        "global_load_dwordx4 %[v8], %[a2], off sc0\n\t"                       \
        "global_load_dwordx4 %[v9], %[a2], off offset:1024 sc0\n\t"           \
        "global_load_dwordx4 %[v10], %[a2], off offset:2048 sc0\n\t"          \
        "global_load_dwordx4 %[v11], %[a2], off offset:3072 sc0\n\t"          \
        "s_waitcnt vmcnt(0)"                                                  \
        : [v0]"=&v"(v[0]), [v1]"=&v"(v[1]), [v2]"=&v"(v[2]), [v3]"=&v"(v[3]), \
          [v4]"=&v"(v[4]), [v5]"=&v"(v[5]), [v6]"=&v"(v[6]), [v7]"=&v"(v[7]), \
          [v8]"=&v"(v[8]), [v9]"=&v"(v[9]), [v10]"=&v"(v[10]), [v11]"=&v"(v[11]) \
        : [a0]"v"(a0_), [a1]"v"(a1_), [a2]"v"(a2_)                            \
        : "memory");

// ---------------- LSTM recurrence ----------------
// R8: tagged-data exchange — h published as u32 {tag<<16 | f16}. Each dword
// self-validates (4B store atomicity), so:
//   - no producer vmcnt drain, no flag store, no flag poll: consumers poll
//     the data words directly (12x dwordx4 sc0, one vmcnt) and the successful
//     iteration already holds h. One L2 round-trip per step instead of three.
//   - tag = tag_base + step + 1 (monotone, layer-disjoint); AND-of-all == tag
//     rejects every stale value (stale < tag cannot contain all tag bits).
//   - lockstep (every block consumes every block each step) bounds skew to
//     one step => 2-row ring; exch = 48KB, stays hot in L2 (no HBM writes).
//   - one barrier/step (gatesS double-buffered), xout fire-and-forget.
// Election (same-XCD placement, capped loops) kept from R5; fillers dropped
// (R7 falsified the clock theory). Fallback: sticky downgrade to agent-scope
// atomic-load polling, then free-run (liveness guaranteed, never triggers).
__launch_bounds__(256,1)
__global__ void lstm_layer_k(const f16* __restrict__ pre,
                             const f16* __restrict__ whh_f,
                             const f16* __restrict__ whh_b,
                             f16* __restrict__ xout,
                             unsigned* __restrict__ exchU,
                             unsigned* __restrict__ elect,
                             unsigned tag_base) {
    int tid = threadIdx.x;
    __shared__ unsigned role_s;
    __shared__ f16 preS[40960];         // 80KB declared (32KB used) -> 1 block/CU
    __shared__ float gatesS[2][1152];   // double-buffered, stride 9 conflict-free
    if (tid == 0) {
        unsigned xcc = get_xcc();
        unsigned r = __hip_atomic_fetch_add(&elect[xcc], 1u,
                        __ATOMIC_RELAXED, __HIP_MEMORY_SCOPE_AGENT);
        if (r == 23u) {                      // this XCD just reached 24 running blocks
            unsigned expected = 0u;
            __hip_atomic_compare_exchange_strong(&elect[8], &expected, xcc + 1u,
                __ATOMIC_RELAXED, __ATOMIC_RELAXED, __HIP_MEMORY_SCOPE_AGENT);
        }
        unsigned win = 0;
        for (int it = 0; it < (1<<20) && !win; ++it) {   // capped: no hang possible
            win = __hip_atomic_load(&elect[8], __ATOMIC_RELAXED, __HIP_MEMORY_SCOPE_AGENT);
            if (!win) __builtin_amdgcn_s_sleep(8);
        }
        unsigned role = 0xFFFFFFFFu;
        if (win == xcc + 1u)
            role = __hip_atomic_fetch_add(&elect[9], 1u,
                        __ATOMIC_RELAXED, __HIP_MEMORY_SCOPE_AGENT);
        role_s = role;
    }
    __syncthreads();
    unsigned role = role_s;
    if (role >= 24u) return;

    int dir = role >= 12u;
    int g   = (int)role - dir*12;
    const f16* W    = dir ? whh_b : whh_f;
    const f16* preD = pre   + (size_t)dir*MTOT*NG;
    unsigned* exchD = exchU + (size_t)dir*2*3072;   // 2-row ring per dir

    int w = tid>>6, l = tid&63;       // wave w == gate index (i,f,g,o)
    int lrow = l&15, lgrp = l>>4;

    // register-resident W_hh B-frags: rows = w*384 + 32g + {0..31}
    f16x8 bf0[12], bf1[12];
    {
        int row0 = w*HDD + g*32 + lrow;
        #pragma unroll
        for (int kk=0; kk<12; kk++)
            bf0[kk] = *(const f16x8*)(W + (size_t)row0*HDD + kk*32 + lgrp*8);
        int row1 = row0 + 16;
        #pragma unroll
        for (int kk=0; kk<12; kk++)
            bf1[kk] = *(const f16x8*)(W + (size_t)row1*HDD + kk*32 + lgrp*8);
    }

    int eb = tid>>5, ejh = tid&31;    // epilogue thread = (batch, jh)
    float c_state = 0.f;
    size_t exch_wr = ((size_t)g*4 + (ejh>>3))*64 + (size_t)eb*8 + (ejh&7);
    size_t mrow = (size_t)eb*TT;
    // poll set: lane (r=l&7, half=(l>>3)&1, lgrp) covers run (kk*4+lgrp, b=r),
    // dwords half*4..half*4+3 -> whole wave covers the entire step's exch.
    unsigned dwoff = (unsigned)(lgrp*64 + (l&7)*8 + ((l>>3)&1)*4);

    // pre staging: block g owns col-blocks wb=2g (wh=0), 2g+1 (wh=1)
    const f16* preB0 = preD + (size_t)(2*g    )*524288;
    const f16* preB1 = preD + (size_t)(2*g + 1)*524288;
    int su = w*4;                     // this wave's first staging unit (of 16)
    // per-step pv read: [wh][b][lc][gate] inside each 1024-f16 slot
    const f16* pread = preS + (size_t)(ejh>>4)*512 + (size_t)eb*64 + (size_t)(ejh&15)*4;

    {   // prologue: stage chunk for steps 0..7 into buf 0
        int tmin = dir ? (TT-8) : 0;
        #pragma unroll
        for (int i=0;i<4;i++) {
            int u = su + i, wh = u>>3, slot = u&7;
            const f16* src = (wh ? preB1 : preB0) + (size_t)(tmin+slot)*512 + l*8;
            gload_lds16(src, preS + slot*1024 + wh*512);
        }
        asm volatile("s_waitcnt vmcnt(0)" ::: "memory");
    }
    __syncthreads();                  // staged chunk visible to all waves

    int fast_ok = 1, dead = 0;        // wave-uniform sticky state
    int plo = l & ~8, phi = l | 8;

    for (int step=0; step<TT; step++) {
        int t = dir ? (TT-1-step) : step;
        int slot = dir ? (7-(step&7)) : (step&7);   // LDS holds t-ascending
        int buf = (step>>3)&1;
        // pre from LDS: 4 gates for this (batch,col) in one 8B ds_read
        f16x4 pv = *(const f16x4*)(pread + buf*8192 + slot*1024);

        f32x4 acc0 = {0,0,0,0}, acc1 = {0,0,0,0};
        if (step > 0) {
            unsigned tagw = tag_base + (unsigned)step;
            const unsigned* b0 = exchD + ((size_t)((step-1)&1))*3072 + dwoff;
            const unsigned* b1 = b0 + 1024;
            const unsigned* b2 = b0 + 2048;
            u32x4 v[12];
            int ok = 0;
            if (fast_ok) {
                for (int it=0; it<2048 && !ok; ++it) {
                    POLL12(v, b0, b1, b2);
                    unsigned a = 0xFFFFFFFFu;
                    #pragma unroll
                    for (int i=0;i<12;i++) a &= v[i][0]&v[i][1]&v[i][2]&v[i][3];
                    ok = __all((a>>16) == tagw);
                }
                if (!ok) fast_ok = 0;       // sticky: sc0 path broken/slow
            }
            if (!ok && !dead) {
                for (int it=0; it<8192 && !ok; ++it) {
                    #pragma unroll
                    for (int i=0;i<12;i++) {
                        #pragma unroll
                        for (int j=0;j<4;j++)
                            v[i][j] = __hip_atomic_load(b0 + i*256 + j,
                                        __ATOMIC_RELAXED, __HIP_MEMORY_SCOPE_AGENT);
                    }
                    unsigned a = 0xFFFFFFFFu;
                    #pragma unroll
                    for (int i=0;i<12;i++) a &= v[i][0]&v[i][1]&v[i][2]&v[i][3];
                    ok = __all((a>>16) == tagw);
                }
                if (!ok) dead = 1;          // protocol failure: free-run
            }
            // extract f16 lanes + cross-half exchange, fused with MFMA.
            // af row = l&7 (rows 8..15 duplicate rows 0..7 -> C rows 8..15,
            // which are never staged). pack(a,b) = {lo16(a), lo16(b)}.
            #pragma unroll
            for (int kk=0; kk<12; kk++) {
                unsigned pk0 = __builtin_amdgcn_perm(v[kk][1], v[kk][0], 0x05040100u);
                unsigned pk1 = __builtin_amdgcn_perm(v[kk][3], v[kk][2], 0x05040100u);
                unsigned d0 = (unsigned)__shfl((int)pk0, plo, 64);
                unsigned d1 = (unsigned)__shfl((int)pk1, plo, 64);
                unsigned d2 = (unsigned)__shfl((int)pk0, phi, 64);
                unsigned d3 = (unsigned)__shfl((int)pk1, phi, 64);
                u32x4 t4; t4[0]=d0; t4[1]=d1; t4[2]=d2; t4[3]=d3;
                f16x8 af; __builtin_memcpy(&af, &t4, 16);
                acc0 = __builtin_amdgcn_mfma_f32_16x16x32_f16(af, bf0[kk], acc0, 0,0,0);
                acc1 = __builtin_amdgcn_mfma_f32_16x16x32_f16(af, bf1[kk], acc1, 0,0,0);
            }
        }
        // stage gates (C layout: col=l&15, row=4*lgrp+r; rows>=8 garbage, not staged)
        int gb = step & 1;
        if (lgrp < 2) {
            int col0 = 32*w + lrow;
            #pragma unroll
            for (int r=0;r<4;r++) gatesS[gb][col0*9 + lgrp*4 + r] = acc0[r];
            int col1 = col0 + 16;
            #pragma unroll
            for (int r=0;r<4;r++) gatesS[gb][col1*9 + lgrp*4 + r] = acc1[r];
        }
        __syncthreads();               // gates visible to epilogue (only barrier)
        float xi = (float)pv[0] + gatesS[gb][(ejh   )*9 + eb];
        float xf = (float)pv[1] + gatesS[gb][(32+ejh)*9 + eb];
        float xg = (float)pv[2] + gatesS[gb][(64+ejh)*9 + eb];
        float xo = (float)pv[3] + gatesS[gb][(96+ejh)*9 + eb];
        float si = 1.f/(1.f+__expf(-xi));
        float sf = 1.f/(1.f+__expf(-xf));
        float eg = __expf(2.f*xg);  float gg = (eg-1.f)/(eg+1.f);
        float so = 1.f/(1.f+__expf(-xo));
        c_state = sf*c_state + si*gg;
        float ec = __expf(2.f*c_state); float tc = (ec-1.f)/(ec+1.f);
        float h = so*tc;
        f16 hh = (f16)h;
        // fire-and-forget tagged publish: {tag, h} in one atomic-visibility dword
        unsigned short hu; __builtin_memcpy(&hu, &hh, 2);
        unsigned pkt = ((tag_base + (unsigned)step + 1u) << 16) | (unsigned)hu;
        *(exchD + ((size_t)(step&1))*3072 + exch_wr) = pkt;
        xout[(mrow + t)*HH + dir*HDD + g*32 + ejh] = hh;
        // stage next pre chunk (once per 8 steps; drained at next poll's
        // vmcnt(0); cross-wave visibility via the per-step barriers)
        if ((step & 7) == 0 && step + 8 < TT) {
            int s0n = step + 8;
            int tmin = dir ? (TT - 8 - s0n) : s0n;
            f16* dstb = preS + ((s0n>>3)&1)*8192;
            #pragma unroll
            for (int i=0;i<4;i++) {
                int u = su + i, wh = u>>3, slot = u&7;
                const f16* src = (wh ? preB1 : preB0) + (size_t)(tmin+slot)*512 + l*8;
                gload_lds16(src, dstb + slot*1024 + wh*512);
            }
        }
    }
}

// ---------------- segment mean pool + MLP + sigmoid ----------------
__global__ void pool_mlp_k(const f16* __restrict__ enc, const int* __restrict__ bounds,
                           const float* __restrict__ w1, const float* __restrict__ b1,
                           const float* __restrict__ w2, const float* __restrict__ b2,
                           float* __restrict__ out) {
    int b = blockIdx.x >> 4, s = blockIdx.x & 15;
    int tid = threadIdx.x;
    int e  = bounds[b*SS + s];
    int st = (s==0) ? 0 : bounds[b*SS + s - 1];
    int len = e - st; if (len < 1) len = 1;
    __shared__ float meanS[HH];
    __shared__ float hS[HDD];
    __shared__ float redS[256];
    for (int dd = tid; dd < HH; dd += 256) {
        float a = 0.f;
        for (int t = st; t < e; t++) a += (float)enc[((size_t)b*TT + t)*HH + dd];
        meanS[dd] = a / (float)len;
    }
    __syncthreads();
    for (int j = tid; j < HDD; j += 256) {
        float a = b1[j];
        const float* wr = w1 + (size_t)j*HH;
        for (int dd = 0; dd < HH; dd++) a += meanS[dd]*wr[dd];
        hS[j] = a > 0.f ? a : 0.f;
    }
    __syncthreads();
    float p = 0.f;
    for (int j = tid; j < HDD; j += 256) p += hS[j]*w2[j];
    redS[tid] = p;
    __syncthreads();
    for (int o = 128; o > 0; o >>= 1) {
        if (tid < o) redS[tid] += redS[tid+o];
        __syncthreads();
    }
    if (tid == 0) {
        float r = 1.f/(1.f+__expf(-(redS[0] + b2[0])));
        out[b*SS + s] = r;
    }
}

__global__ void finalize_k(float* __restrict__ out) {
    int b = threadIdx.x;
    if (b < BB) {
        float m = 1e30f;
        for (int s=0;s<SS;s++) {
            float r = out[b*SS+s];
            float mask = (r > 0.f) ? 1.f : 0.f;
            float v = r*mask + (1.f-mask);
            m = fminf(m, v);
        }
        out[BB*SS + b] = m;
    }
}

extern "C" void kernel_launch(void* const* d_in, const int* in_sizes, int n_in,
                              void* d_out, int out_size, void* d_ws, size_t ws_size,
                              hipStream_t stream) {
    const int*   ids    = (const int*)d_in[0];
    const int*   bounds = (const int*)d_in[1];
    const float* emb    = (const float*)d_in[2];
    const float* wih[4]; const float* whh[4]; const float* bih[4]; const float* bhh[4];
    for (int i=0;i<4;i++) {                // order: l0f, l0b, l1f, l1b
        wih[i] = (const float*)d_in[3 + 4*i];
        whh[i] = (const float*)d_in[4 + 4*i];
        bih[i] = (const float*)d_in[5 + 4*i];
        bhh[i] = (const float*)d_in[6 + 4*i];
    }
    const float* w1 = (const float*)d_in[19];
    const float* b1 = (const float*)d_in[20];
    const float* w2 = (const float*)d_in[21];
    const float* b2 = (const float*)d_in[22];
    float* out = (float*)d_out;

    char* ws = (char*)d_ws;
    size_t off = 0;
    auto alloc = [&](size_t bytes) -> void* {
        void* p = ws + off;
        off += (bytes + 255) & ~(size_t)255;
        return p;
    };
    f16* x0    = (f16*)alloc((size_t)MTOT*HH*2);      // layer0 input; reused as enc
    f16* x1    = (f16*)alloc((size_t)MTOT*HH*2);      // layer0 output / layer1 input
    f16* pre   = (f16*)alloc((size_t)2*MTOT*NG*2);    // pre-activations (reused per layer)
    unsigned* exchU = (unsigned*)alloc((size_t)2*2*3072*4 + 4096); // tagged 2-row ring
    f16* wihh[4]; for (int i=0;i<4;i++) wihh[i] = (f16*)alloc((size_t)NG*HH*2);
    f16* whhh[4]; for (int i=0;i<4;i++) whhh[i] = (f16*)alloc((size_t)NG*HDD*2);
    float* bsum = (float*)alloc((size_t)4*NG*4);
    unsigned* elect = (unsigned*)alloc((size_t)2*16*4);
    f16* enc = x0;

    hipMemsetAsync(exchU, 0, (size_t)2*2*3072*4, stream);
    hipMemsetAsync(elect, 0, (size_t)2*16*4, stream);
    for (int i=0;i<4;i++)
        cast_f32_f16_k<<<(NG*HH+255)/256,256,0,stream>>>(wih[i], wihh[i], NG*HH);
    for (int i=0;i<4;i++)
        cast_f32_f16_k<<<(NG*HDD+255)/256,256,0,stream>>>(whh[i], whhh[i], NG*HDD);
    bias_sum_k<<<(4*NG+255)/256,256,0,stream>>>(bih[0],bhh[0],bih[1],bhh[1],
                                                bih[2],bhh[2],bih[3],bhh[3],bsum);
    embed_cast_k<<<(MTOT*HH+255)/256,256,0,stream>>>(ids, emb, x0);

    dim3 gg(MTOT/64, NG/64, 2);
    gemm_pre_k<<<gg,256,0,stream>>>(x0, wihh[0], wihh[1], bsum, pre);
    lstm_layer_k<<<256,256,0,stream>>>(pre, whhh[0], whhh[1], x1, exchU, elect, 0u);
    gemm_pre_k<<<gg,256,0,stream>>>(x1, wihh[2], wihh[3], bsum + 2*NG, pre);
    lstm_layer_k<<<256,256,0,stream>>>(pre, whhh[2], whhh[3], enc, exchU, elect + 16, 1024u);
    pool_mlp_k<<<BB*SS,256,0,stream>>>(enc, bounds, w1, b1, w2, b2, out);
    finalize_k<<<1,64,0,stream>>>(out);
}

// Round 4
// 4258.744 us; speedup vs baseline: 2.9252x; 2.9252x over previous
//
#include <hip/hip_runtime.h>

typedef _Float16 f16;
typedef _Float16 f16x4 __attribute__((ext_vector_type(4)));
typedef _Float16 f16x8 __attribute__((ext_vector_type(8)));
typedef float f32x4 __attribute__((ext_vector_type(4)));
typedef unsigned u32x4 __attribute__((ext_vector_type(4)));

#define BB 8
#define TT 1024
#define HH 768
#define HDD 384
#define NG 1536        // 4*HDD
#define SS 16
#define MTOT (BB*TT)   // 8192

// ---------------- casts ----------------
__global__ void cast_f32_f16_k(const float* __restrict__ src, f16* __restrict__ dst, int n) {
    int i = blockIdx.x*256 + threadIdx.x;
    if (i < n) dst[i] = (f16)src[i];
}

__global__ void bias_sum_k(const float* a0,const float* b0,const float* a1,const float* b1,
                           const float* a2,const float* b2,const float* a3,const float* b3,
                           float* __restrict__ out) {
    int i = blockIdx.x*256 + threadIdx.x;
    if (i >= 4*NG) return;
    int which = i/NG, j = i - which*NG;
    const float* pa = which==0?a0:which==1?a1:which==2?a2:a3;
    const float* pb = which==0?b0:which==1?b1:which==2?b2:b3;
    out[i] = pa[j] + pb[j];
}

__global__ void embed_cast_k(const int* __restrict__ ids, const float* __restrict__ emb,
                             f16* __restrict__ x) {
    int i = blockIdx.x*256 + threadIdx.x;   // < MTOT*HH
    if (i < MTOT*HH) {
        int m = i / HH;
        int k = i - m*HH;
        x[i] = (f16)emb[(size_t)ids[m]*HH + k];
    }
}

// ---------------- input GEMM ----------------
// R8 layout (validated): pre[dir][wb][t][b][lc][gate], wb=c/16 (0..23), lc=c%16.
// Per (wb,t): 512 f16 = 1KB contiguous -> bulk global_load_lds staging.
__launch_bounds__(256,1)
__global__ void gemm_pre_k(const f16* __restrict__ A, const f16* __restrict__ Wf,
                           const f16* __restrict__ Wb, const float* __restrict__ bsum2,
                           f16* __restrict__ pre) {
    int d = blockIdx.z;
    const f16* Wt = d ? Wb : Wf;
    const float* bs = bsum2 + d*NG;
    f16* out = pre + (size_t)d*MTOT*NG;
    int m0 = blockIdx.x*64, n0 = blockIdx.y*64;
    __shared__ f16 As[64*72];
    __shared__ f16 Bs[64*72];
    int tid = threadIdx.x;
    int w = tid>>6, l = tid&63;
    int lrow = l&15, lgrp = l>>4;
    int mq = (w>>1)*32, nq = (w&1)*32;
    f32x4 acc00={0,0,0,0}, acc01={0,0,0,0}, acc10={0,0,0,0}, acc11={0,0,0,0};

    for (int k0=0; k0<HH; k0+=64) {
        __syncthreads();
        #pragma unroll
        for (int r=0;r<2;r++) {
            int c = tid + 256*r;
            int row = c>>3, seg = c&7;
            *(f16x8*)(As + row*72 + seg*8) = *(const f16x8*)(A  + ((size_t)(m0+row))*HH + k0 + seg*8);
            *(f16x8*)(Bs + row*72 + seg*8) = *(const f16x8*)(Wt + ((size_t)(n0+row))*HH + k0 + seg*8);
        }
        __syncthreads();
        #pragma unroll
        for (int kk=0; kk<64; kk+=32) {
            f16x8 a0 = *(const f16x8*)(As + (mq+lrow)*72    + kk + lgrp*8);
            f16x8 a1 = *(const f16x8*)(As + (mq+16+lrow)*72 + kk + lgrp*8);
            f16x8 b0 = *(const f16x8*)(Bs + (nq+lrow)*72    + kk + lgrp*8);
            f16x8 b1 = *(const f16x8*)(Bs + (nq+16+lrow)*72 + kk + lgrp*8);
            acc00 = __builtin_amdgcn_mfma_f32_16x16x32_f16(a0,b0,acc00,0,0,0);
            acc01 = __builtin_amdgcn_mfma_f32_16x16x32_f16(a0,b1,acc01,0,0,0);
            acc10 = __builtin_amdgcn_mfma_f32_16x16x32_f16(a1,b0,acc10,0,0,0);
            acc11 = __builtin_amdgcn_mfma_f32_16x16x32_f16(a1,b1,acc11,0,0,0);
        }
    }
    #pragma unroll
    for (int mt=0;mt<2;mt++) {
        #pragma unroll
        for (int nt=0;nt<2;nt++) {
            f32x4 a = (mt==0)?(nt==0?acc00:acc01):(nt==0?acc10:acc11);
            int col = n0 + nq + nt*16 + lrow;     // 0..1535 = gate*384 + c
            int gate = col / HDD;
            int c = col - gate*HDD;               // 0..383
            float bv = bs[col];
            size_t base = (size_t)(c>>4)*524288 + (size_t)(c&15)*4 + gate;
            #pragma unroll
            for (int r=0;r<4;r++) {
                int row = m0 + mq + mt*16 + lgrp*4 + r;   // b*1024 + t
                int b = row >> 10, t = row & 1023;
                out[base + (size_t)t*512 + b*64] = (f16)(a[r] + bv);
            }
        }
    }
}

// ---- helpers ----
__device__ __forceinline__ unsigned ld_u32_sc0(const unsigned* p) {
    unsigned v;
    asm volatile("global_load_dword %0, %1, off sc0\n\ts_waitcnt vmcnt(0)"
                 : "=v"(v) : "v"(p) : "memory");
    return v;
}
__device__ __forceinline__ unsigned get_xcc() {
    unsigned x;
    asm("s_getreg_b32 %0, hwreg(HW_REG_XCC_ID)" : "=s"(x));
    return x & 7u;
}
__device__ __forceinline__ void gload_lds16(const f16* g, f16* lds) {
    __builtin_amdgcn_global_load_lds(
        (const __attribute__((address_space(1))) void*)g,
        (__attribute__((address_space(3))) void*)lds, 16, 0, 0);
}

// one-shot exch gather: 12x dwordx4 sc0 (L1-bypass: ring rows repeat every 2
// steps, plain loads would hit stale L1) + ONE vmcnt. kk-stride 512B.
#define GATHER12(v, a0_, a1_)                                                 \
    asm volatile(                                                             \
        "global_load_dwordx4 %[v0], %[a0], off sc0\n\t"                       \
        "global_load_dwordx4 %[v1], %[a0], off offset:512 sc0\n\t"            \
        "global_load_dwordx4 %[v2], %[a0], off offset:1024 sc0\n\t"           \
        "global_load_dwordx4 %[v3], %[a0], off offset:1536 sc0\n\t"           \
        "global_load_dwordx4 %[v4], %[a0], off offset:2048 sc0\n\t"           \
        "global_load_dwordx4 %[v5], %[a0], off offset:2560 sc0\n\t"           \
        "global_load_dwordx4 %[v6], %[a0], off offset:3072 sc0\n\t"           \
        "global_load_dwordx4 %[v7], %[a0], off offset:3584 sc0\n\t"           \
        "global_load_dwordx4 %[v8], %[a1], off sc0\n\t"                       \
        "global_load_dwordx4 %[v9], %[a1], off offset:512 sc0\n\t"            \
        "global_load_dwordx4 %[v10], %[a1], off offset:1024 sc0\n\t"          \
        "global_load_dwordx4 %[v11], %[a1], off offset:1536 sc0\n\t"          \
        "s_waitcnt vmcnt(0)"                                                  \
        : [v0]"=&v"(v[0]), [v1]"=&v"(v[1]), [v2]"=&v"(v[2]), [v3]"=&v"(v[3]), \
          [v4]"=&v"(v[4]), [v5]"=&v"(v[5]), [v6]"=&v"(v[6]), [v7]"=&v"(v[7]), \
          [v8]"=&v"(v[8]), [v9]"=&v"(v[9]), [v10]"=&v"(v[10]), [v11]"=&v"(v[11]) \
        : [a0]"v"(a0_), [a1]"v"(a1_)                                          \
        : "memory");

// ---------------- LSTM recurrence ----------------
// R9 = R5 protocol shape (skinny flag poll + ONE-shot data gather) with the
// step loop's outstanding-store set minimized:
//  - xout removed from the step loop: h staged per-thread in LDS, ONE 16B
//    coalesced store per 8 steps into transposed hT[col][b][t] (full lines,
//    ACK amortized 1/8). A separate transpose kernel rebuilds [m][k] for the
//    next GEMM; pool reads hT directly (stride-1 over t).
//  - per-WAVE flags (48/dir, value = step+1, 16-deep ring): each wave drains
//    only its own 128B exch store (vmcnt(0)) then lane0 publishes. No
//    publish barrier, no tid0 serialization.
//  - exch = 2-row L2-hot ring (R8-proven WRITE_SIZE halving); consumers read
//    it ONCE per step via GATHER12 sc0 (R8's failure was REPEATED data polls).
//  - one barrier/step (double-buffered gatesS); MFMA accs split even/odd kk
//    (chain 12 -> 6); pre staged to LDS (R8 layout, 4-way not 16-way).
// Election + capped fast/safe/dead fallback identical to R5.
__launch_bounds__(256,1)
__global__ void lstm_layer_k(const f16* __restrict__ pre,
                             const f16* __restrict__ whh_f,
                             const f16* __restrict__ whh_b,
                             f16* __restrict__ hT,
                             f16* __restrict__ exch,
                             unsigned* __restrict__ flags_fast,
                             unsigned* __restrict__ flags_safe,
                             unsigned* __restrict__ elect) {
    int tid = threadIdx.x;
    __shared__ unsigned role_s;
    __shared__ f16 preS[16384];        // 32KB: [buf2][slot8][1024]
    __shared__ float gatesS[2][1152];  // double-buffered, stride 9
    __shared__ f16 hstageS[256*8];     // 4KB: per-thread 8-step h stage
    if (tid == 0) {
        unsigned xcc = get_xcc();
        unsigned r = __hip_atomic_fetch_add(&elect[xcc], 1u,
                        __ATOMIC_RELAXED, __HIP_MEMORY_SCOPE_AGENT);
        if (r == 23u) {                      // this XCD just reached 24 running blocks
            unsigned expected = 0u;
            __hip_atomic_compare_exchange_strong(&elect[8], &expected, xcc + 1u,
                __ATOMIC_RELAXED, __ATOMIC_RELAXED, __HIP_MEMORY_SCOPE_AGENT);
        }
        unsigned win = 0;
        for (int it = 0; it < (1<<20) && !win; ++it) {   // capped: no hang possible
            win = __hip_atomic_load(&elect[8], __ATOMIC_RELAXED, __HIP_MEMORY_SCOPE_AGENT);
            if (!win) __builtin_amdgcn_s_sleep(8);
        }
        unsigned role = 0xFFFFFFFFu;
        if (win == xcc + 1u)
            role = __hip_atomic_fetch_add(&elect[9], 1u,
                        __ATOMIC_RELAXED, __HIP_MEMORY_SCOPE_AGENT);
        role_s = role;
    }
    __syncthreads();
    unsigned role = role_s;
    if (role >= 24u) return;

    int dir = role >= 12u;
    int g   = (int)role - dir*12;
    const f16* W    = dir ? whh_b : whh_f;
    const f16* preD = pre  + (size_t)dir*MTOT*NG;
    f16* exchD      = exch + (size_t)dir*2*3072;        // 2-row ring per dir
    unsigned* ffD   = flags_fast + dir*2048;            // [wid 0..63][ring16]
    unsigned* fsD   = flags_safe + dir*2048;

    int w = tid>>6, l = tid&63;       // wave w == gate index (i,f,g,o)
    int lrow = l&15, lgrp = l>>4;
    int wfid = g*4 + w;               // per-wave flag id (0..47)

    // register-resident W_hh B-frags: rows = w*384 + 32g + {0..31}
    f16x8 bf0[12], bf1[12];
    {
        int row0 = w*HDD + g*32 + lrow;
        #pragma unroll
        for (int kk=0; kk<12; kk++)
            bf0[kk] = *(const f16x8*)(W + (size_t)row0*HDD + kk*32 + lgrp*8);
        int row1 = row0 + 16;
        #pragma unroll
        for (int kk=0; kk<12; kk++)
            bf1[kk] = *(const f16x8*)(W + (size_t)row1*HDD + kk*32 + lgrp*8);
    }

    int eb = tid>>5, ejh = tid&31;    // epilogue thread = (batch, jh)
    float c_state = 0.f;
    size_t exch_wr = ((size_t)g*4 + (ejh>>3))*64 + (size_t)eb*8 + (ejh&7);
    int cthr = g*32 + ejh;            // this thread's output column
    f16* hT_base = hT + ((size_t)(dir*HDD + cthr)*BB + eb)*TT;

    // pre staging: block g owns col-blocks wb=2g (wh=0), 2g+1 (wh=1)
    const f16* preB0 = preD + (size_t)(2*g    )*524288;
    const f16* preB1 = preD + (size_t)(2*g + 1)*524288;
    int su = w*4;                     // this wave's first staging unit (of 16)
    const f16* pread = preS + (size_t)(ejh>>4)*512 + (size_t)eb*64 + (size_t)(ejh&15)*4;

    {   // prologue: stage chunk for steps 0..7 into buf 0
        int tmin = dir ? (TT-8) : 0;
        #pragma unroll
        for (int i=0;i<4;i++) {
            int u = su + i, wh = u>>3, slot = u&7;
            const f16* src = (wh ? preB1 : preB0) + (size_t)(tmin+slot)*512 + l*8;
            gload_lds16(src, preS + slot*1024 + wh*512);
        }
        asm volatile("s_waitcnt vmcnt(0)" ::: "memory");
    }
    __syncthreads();                  // staged chunk visible to all waves

    int fast_ok = 1, dead = 0;        // wave-uniform sticky state

    for (int step=0; step<TT; step++) {
        int t = dir ? (TT-1-step) : step;
        int slot = dir ? (7-(step&7)) : (step&7);   // LDS holds t-ascending
        int buf = (step>>3)&1;
        f16x4 pv = *(const f16x4*)(pread + buf*8192 + slot*1024);

        f32x4 acc0a={0,0,0,0}, acc0b={0,0,0,0}, acc1a={0,0,0,0}, acc1b={0,0,0,0};
        if (step > 0) {
            // skinny detect: 48 lanes poll one flag dword each
            unsigned want = (unsigned)step;          // = (step-1)+1
            unsigned got = (l < 48) ? 0u : want;
            const unsigned* fp = ffD + (size_t)l*32 + ((step-1)&15);
            if (fast_ok) {
                for (int it=0; it<1024 && !__all(got==want); ++it)
                    if (got != want) got = ld_u32_sc0(fp);
                if (!__all(got==want)) fast_ok = 0;  // sticky: sc0 path broken/slow
            }
            if (!__all(got==want) && !dead) {
                const unsigned* sp = fsD + (size_t)l*32 + ((step-1)&15);
                for (int it=0; it<8192 && !__all(got==want); ++it)
                    if (got != want) got = __hip_atomic_load(sp, __ATOMIC_RELAXED,
                                                             __HIP_MEMORY_SCOPE_AGENT);
                if (!__all(got==want)) dead = 1;     // protocol failure: free-run
            }
            // one-shot gather of h_{t-1} (ring row (step-1)&1, L2-hot, sc0).
            // lanes lrow>=8 read slack -> C rows 8..15, never staged.
            const f16* p0 = exchD + ((size_t)((step-1)&1))*3072 + lgrp*64 + lrow*8;
            const f16* p1 = p0 + 2048;
            u32x4 av[12];
            GATHER12(av, p0, p1);
            f16x8 af[12];
            #pragma unroll
            for (int kk=0;kk<12;kk++) __builtin_memcpy(&af[kk], &av[kk], 16);
            #pragma unroll
            for (int kk=0;kk<12;kk+=2) {
                acc0a = __builtin_amdgcn_mfma_f32_16x16x32_f16(af[kk],   bf0[kk],   acc0a, 0,0,0);
                acc1a = __builtin_amdgcn_mfma_f32_16x16x32_f16(af[kk],   bf1[kk],   acc1a, 0,0,0);
                acc0b = __builtin_amdgcn_mfma_f32_16x16x32_f16(af[kk+1], bf0[kk+1], acc0b, 0,0,0);
                acc1b = __builtin_amdgcn_mfma_f32_16x16x32_f16(af[kk+1], bf1[kk+1], acc1b, 0,0,0);
            }
        }
        // stage gates (C layout: col=l&15, row=4*lgrp+r; rows>=8 garbage, not staged)
        int gb = step & 1;
        if (lgrp < 2) {
            int col0 = 32*w + lrow;
            #pragma unroll
            for (int r=0;r<4;r++) gatesS[gb][col0*9 + lgrp*4 + r] = acc0a[r] + acc0b[r];
            int col1 = col0 + 16;
            #pragma unroll
            for (int r=0;r<4;r++) gatesS[gb][col1*9 + lgrp*4 + r] = acc1a[r] + acc1b[r];
        }
        __syncthreads();               // only barrier: gates visible to epilogue
        float xi = (float)pv[0] + gatesS[gb][(ejh   )*9 + eb];
        float xf = (float)pv[1] + gatesS[gb][(32+ejh)*9 + eb];
        float xg = (float)pv[2] + gatesS[gb][(64+ejh)*9 + eb];
        float xo = (float)pv[3] + gatesS[gb][(96+ejh)*9 + eb];
        float si = 1.f/(1.f+__expf(-xi));
        float sf = 1.f/(1.f+__expf(-xf));
        float eg = __expf(2.f*xg);  float gg = (eg-1.f)/(eg+1.f);
        float so = 1.f/(1.f+__expf(-xo));
        c_state = sf*c_state + si*gg;
        float ec = __expf(2.f*c_state); float tc = (ec-1.f)/(ec+1.f);
        float h = so*tc;
        f16 hh = (f16)h;
        // exch packet: (even,odd) col pair -> one 4B store into ring row step&1
        unsigned short hu; __builtin_memcpy(&hu, &hh, 2);
        unsigned short pu = (unsigned short)__shfl_xor((int)hu, 1, 64);
        if ((ejh & 1) == 0) {
            unsigned pkt = (unsigned)hu | ((unsigned)pu << 16);
            *(unsigned*)(exchD + ((size_t)(step&1))*3072 + exch_wr) = pkt;
        }
        // per-wave publish: drain ONLY this wave's tiny exch store, then flag
        asm volatile("s_waitcnt vmcnt(0)" ::: "memory");
        if (l == 0) {
            ffD[(size_t)wfid*32 + (step&15)] = (unsigned)step + 1u;   // fast (plain)
            __hip_atomic_store(fsD + (size_t)wfid*32 + (step&15), (unsigned)step + 1u,
                               __ATOMIC_RELAXED, __HIP_MEMORY_SCOPE_AGENT);  // safe
        }
        // h output: LDS stage now; one coalesced 16B store per 8 steps.
        // Fire-and-forget: ACK drains in a later poll, off the publish path.
        hstageS[tid*8 + slot] = hh;
        if ((step & 7) == 7) {
            f16x8 hv = *(const f16x8*)(hstageS + tid*8);
            *(f16x8*)(hT_base + (t & ~7)) = hv;
        }
        // stage next pre chunk (once per 8 steps; drains at next step's poll)
        if ((step & 7) == 0 && step + 8 < TT) {
            int s0n = step + 8;
            int tmin = dir ? (TT - 8 - s0n) : s0n;
            f16* dstb = preS + ((s0n>>3)&1)*8192;
            #pragma unroll
            for (int i=0;i<4;i++) {
                int u = su + i, wh = u>>3, slot2 = u&7;
                const f16* src = (wh ? preB1 : preB0) + (size_t)(tmin+slot2)*512 + l*8;
                gload_lds16(src, dstb + slot2*1024 + wh*512);
            }
        }
    }
}

// ---------------- transpose hT[col][b][t] -> x[m][k] for the next GEMM ----------------
__global__ void transpose_hT_k(const f16* __restrict__ hT, f16* __restrict__ x) {
    int bi = blockIdx.x;              // 3072 blocks
    int tid = threadIdx.x;
    int l = tid & 63, w = tid >> 6;
    int tb4 = bi & 31;
    int b   = (bi >> 5) & 7;
    int d64 = bi >> 8;                // 0..11
    int dirc = d64*64 + l;
    int t0 = (tb4*4 + w)*8;
    f16x8 v = *(const f16x8*)(hT + ((size_t)dirc*BB + b)*TT + t0);
    #pragma unroll
    for (int j=0;j<8;j++)             // writes coalesced across lanes per j
        x[((size_t)b*TT + t0 + j)*HH + dirc] = v[j];
}

// ---------------- segment mean pool + MLP + sigmoid ----------------
// reads hT directly: [dd][b][t] -> stride-1 over t (better than old stride-768)
__global__ void pool_mlp_k(const f16* __restrict__ encT, const int* __restrict__ bounds,
                           const float* __restrict__ w1, const float* __restrict__ b1,
                           const float* __restrict__ w2, const float* __restrict__ b2,
                           float* __restrict__ out) {
    int b = blockIdx.x >> 4, s = blockIdx.x & 15;
    int tid = threadIdx.x;
    int e  = bounds[b*SS + s];
    int st = (s==0) ? 0 : bounds[b*SS + s - 1];
    int len = e - st; if (len < 1) len = 1;
    __shared__ float meanS[HH];
    __shared__ float hS[HDD];
    __shared__ float redS[256];
    for (int dd = tid; dd < HH; dd += 256) {
        float a = 0.f;
        const f16* row = encT + ((size_t)dd*BB + b)*TT;
        for (int t = st; t < e; t++) a += (float)row[t];
        meanS[dd] = a / (float)len;
    }
    __syncthreads();
    for (int j = tid; j < HDD; j += 256) {
        float a = b1[j];
        const float* wr = w1 + (size_t)j*HH;
        for (int dd = 0; dd < HH; dd++) a += meanS[dd]*wr[dd];
        hS[j] = a > 0.f ? a : 0.f;
    }
    __syncthreads();
    float p = 0.f;
    for (int j = tid; j < HDD; j += 256) p += hS[j]*w2[j];
    redS[tid] = p;
    __syncthreads();
    for (int o = 128; o > 0; o >>= 1) {
        if (tid < o) redS[tid] += redS[tid+o];
        __syncthreads();
    }
    if (tid == 0) {
        float r = 1.f/(1.f+__expf(-(redS[0] + b2[0])));
        out[b*SS + s] = r;
    }
}

__global__ void finalize_k(float* __restrict__ out) {
    int b = threadIdx.x;
    if (b < BB) {
        float m = 1e30f;
        for (int s=0;s<SS;s++) {
            float r = out[b*SS+s];
            float mask = (r > 0.f) ? 1.f : 0.f;
            float v = r*mask + (1.f-mask);
            m = fminf(m, v);
        }
        out[BB*SS + b] = m;
    }
}

extern "C" void kernel_launch(void* const* d_in, const int* in_sizes, int n_in,
                              void* d_out, int out_size, void* d_ws, size_t ws_size,
                              hipStream_t stream) {
    const int*   ids    = (const int*)d_in[0];
    const int*   bounds = (const int*)d_in[1];
    const float* emb    = (const float*)d_in[2];
    const float* wih[4]; const float* whh[4]; const float* bih[4]; const float* bhh[4];
    for (int i=0;i<4;i++) {                // order: l0f, l0b, l1f, l1b
        wih[i] = (const float*)d_in[3 + 4*i];
        whh[i] = (const float*)d_in[4 + 4*i];
        bih[i] = (const float*)d_in[5 + 4*i];
        bhh[i] = (const float*)d_in[6 + 4*i];
    }
    const float* w1 = (const float*)d_in[19];
    const float* b1 = (const float*)d_in[20];
    const float* w2 = (const float*)d_in[21];
    const float* b2 = (const float*)d_in[22];
    float* out = (float*)d_out;

    char* ws = (char*)d_ws;
    size_t off = 0;
    auto alloc = [&](size_t bytes) -> void* {
        void* p = ws + off;
        off += (bytes + 255) & ~(size_t)255;
        return p;
    };
    f16* x0    = (f16*)alloc((size_t)MTOT*HH*2);      // embedding (layer0 input)
    f16* x1    = (f16*)alloc((size_t)MTOT*HH*2);      // transposed layer0 out
    f16* pre   = (f16*)alloc((size_t)2*MTOT*NG*2);    // pre-activations
    f16* hT    = (f16*)alloc((size_t)HH*BB*TT*2);     // lstm out [dirc][b][t], reused
    f16* exch  = (f16*)alloc((size_t)2*2*3072*2 + 4096); // 2-row ring/dir + slack
    f16* wihh[4]; for (int i=0;i<4;i++) wihh[i] = (f16*)alloc((size_t)NG*HH*2);
    f16* whhh[4]; for (int i=0;i<4;i++) whhh[i] = (f16*)alloc((size_t)NG*HDD*2);
    float* bsum = (float*)alloc((size_t)4*NG*4);
    // flags: [layer][dir][wid64][ring16], 128B stride per wid
    unsigned* flags_fast = (unsigned*)alloc((size_t)2*2*64*16*4);
    unsigned* flags_safe = (unsigned*)alloc((size_t)2*2*64*16*4);
    unsigned* elect      = (unsigned*)alloc((size_t)2*16*4);

    hipMemsetAsync(flags_fast, 0, (size_t)2*2*64*16*4, stream);
    hipMemsetAsync(flags_safe, 0, (size_t)2*2*64*16*4, stream);
    hipMemsetAsync(elect,      0, (size_t)2*16*4, stream);
    for (int i=0;i<4;i++)
        cast_f32_f16_k<<<(NG*HH+255)/256,256,0,stream>>>(wih[i], wihh[i], NG*HH);
    for (int i=0;i<4;i++)
        cast_f32_f16_k<<<(NG*HDD+255)/256,256,0,stream>>>(whh[i], whhh[i], NG*HDD);
    bias_sum_k<<<(4*NG+255)/256,256,0,stream>>>(bih[0],bhh[0],bih[1],bhh[1],
                                                bih[2],bhh[2],bih[3],bhh[3],bsum);
    embed_cast_k<<<(MTOT*HH+255)/256,256,0,stream>>>(ids, emb, x0);

    dim3 gg(MTOT/64, NG/64, 2);
    gemm_pre_k<<<gg,256,0,stream>>>(x0, wihh[0], wihh[1], bsum, pre);
    lstm_layer_k<<<256,256,0,stream>>>(pre, whhh[0], whhh[1], hT, exch,
                                       flags_fast, flags_safe, elect);
    transpose_hT_k<<<3072,256,0,stream>>>(hT, x1);
    gemm_pre_k<<<gg,256,0,stream>>>(x1, wihh[2], wihh[3], bsum + 2*NG, pre);
    lstm_layer_k<<<256,256,0,stream>>>(pre, whhh[2], whhh[3], hT, exch,
                                       flags_fast + 4096, flags_safe + 4096,
                                       elect + 16);
    pool_mlp_k<<<BB*SS,256,0,stream>>>(hT, bounds, w1, b1, w2, b2, out);
    finalize_k<<<1,64,0,stream>>>(out);
}